// Round 8
// baseline (3897.255 us; speedup 1.0000x reference)
//
#include <hip/hip_runtime.h>

#define NN 50000
#define DD 64
#define EE 800000
#define NF 200000            // 4*NN flat nodes
#define BROW 128             // dst nodes per bucket
#define NBK 1563             // ceil(NF/BROW)
#define NCHK 49              // bin blocks per relation
#define CHUNK 16384
#define STCAP 2304           // staged edges per gather chunk
#define BN_EPS 1e-5f
#define NEG 0.01f

typedef float4 f4;

__device__ __forceinline__ float b2f(unsigned short u) {
    return __uint_as_float(((unsigned)u) << 16);
}
__device__ __forceinline__ unsigned short f2b(float x) {
    unsigned u = __float_as_uint(x);
    u += 0x7fffu + ((u >> 16) & 1u);   // RNE
    return (unsigned short)(u >> 16);
}

__device__ __forceinline__ const int* esel(int k, const int* e0, const int* e1,
                                           const int* e2, const int* e3) {
    return (k == 0) ? e0 : (k == 1) ? e1 : (k == 2) ? e2 : e3;
}

// ---- bucket histogram (blocks 0..195) + rels/stats-zero (block 196) ----
__global__ __launch_bounds__(256) void k_hist_rels(
    const int* __restrict__ e0, const int* __restrict__ e1,
    const int* __restrict__ e2, const int* __restrict__ e3,
    int* __restrict__ ghist,
    const float* __restrict__ nr, const float* __restrict__ poir,
    const float* __restrict__ sr, const float* __restrict__ dr,
    const float* __restrict__ relW, const float* __restrict__ relb,
    float* __restrict__ rels_all, float* __restrict__ rel_out,
    float* __restrict__ stats) {
    int tid = threadIdx.x;
    if (blockIdx.x < 196) {
        __shared__ int hist[NBK];
        int k = blockIdx.x / NCHK;
        int cb = blockIdx.x - k * NCHK;
        const int* ed = esel(k, e0, e1, e2, e3);
        int lo = cb * CHUNK, hi = min(EE, lo + CHUNK);
        for (int i = tid; i < NBK; i += 256) hist[i] = 0;
        __syncthreads();
        for (int i = lo + tid; i < hi; i += 256)
            atomicAdd(&hist[(k * NN + ed[EE + i]) >> 7], 1);
        __syncthreads();
        for (int i = tid; i < NBK; i += 256) {
            int c = hist[i];
            if (c) atomicAdd(&ghist[i], c);
        }
    } else {
        __shared__ float cur[4][64];
        stats[tid] = 0.f; stats[tid + 256] = 0.f;
        stats[tid + 512] = 0.f; stats[tid + 768] = 0.f;
        int k = tid >> 6, j = tid & 63;
        const float* r0 = (k == 0) ? nr : (k == 1) ? poir : (k == 2) ? sr : dr;
        float v = r0[j];
        cur[k][j] = v;
        rels_all[(0 * 4 + k) * 64 + j] = v;
        __syncthreads();
        for (int s = 0; s < 3; ++s) {
            const float* W = relW + s * 4096;
            float acc = relb[s * 64 + j];
            #pragma unroll 8
            for (int kk = 0; kk < 64; ++kk) acc += cur[k][kk] * W[j * 64 + kk];
            __syncthreads();
            cur[k][j] = acc;
            rels_all[((s + 1) * 4 + k) * 64 + j] = acc;
            __syncthreads();
        }
        rel_out[k * 64 + j] = cur[k][j];
    }
}

// ---- exclusive scan of 1563 bucket counts -> gbase (+sentinel), gcur ----
__global__ __launch_bounds__(256) void k_scanbk(const int* __restrict__ ghist,
                                                int* __restrict__ gbase,
                                                int* __restrict__ gcur) {
    __shared__ int s[256];
    __shared__ int carry;
    int tid = threadIdx.x;
    if (tid == 0) carry = 0;
    __syncthreads();
    for (int base = 0; base < NBK; base += 256) {
        int i = base + tid;
        int v = (i < NBK) ? ghist[i] : 0;
        s[tid] = v;
        __syncthreads();
        for (int d = 1; d < 256; d <<= 1) {
            int t = (tid >= d) ? s[tid - d] : 0;
            __syncthreads();
            s[tid] += t;
            __syncthreads();
        }
        int c = carry;
        if (i < NBK) { gbase[i] = s[tid] - v + c; gcur[i] = s[tid] - v + c; }
        __syncthreads();
        if (tid == 0) carry = c + s[255];
        __syncthreads();
    }
    if (tid == 0) gbase[NBK] = carry;   // = 4*EE
}

// ---- shared GEMM body: [optional BN+leaky+residual] then h_bf = (e.*rel)@W ----
__device__ __forceinline__ void gemm_body(
    float* __restrict__ Wl, float (*__restrict__ xl)[68], int bxl, int tid,
    const float* __restrict__ prevbuf, size_t prev_ka_stride,
    const float* __restrict__ agg, const float* __restrict__ stats,
    const float* __restrict__ gamma, const float* __restrict__ beta,
    const float* __restrict__ rels, const float* __restrict__ W,
    float* __restrict__ e1, unsigned short* __restrict__ h_bf, int mode) {
    int ka = bxl / 3125;
    int row0 = (bxl - ka * 3125) * 16;
    {
        const f4* W4 = (const f4*)W;
        f4* Wl4 = (f4*)Wl;
        Wl4[tid] = W4[tid];
        Wl4[tid + 256] = W4[tid + 256];
        Wl4[tid + 512] = W4[tid + 512];
        Wl4[tid + 768] = W4[tid + 768];
    }
    int rl = tid >> 4, c4 = (tid & 15) * 4;
    int row = row0 + rl;
    size_t kabase = (size_t)ka * NN * DD;
    {
        f4 pv = *(const f4*)(prevbuf + (size_t)ka * prev_ka_stride + (size_t)row * DD + c4);
        if (mode > 0) {
            f4 av = *(const f4*)(agg + kabase + (size_t)row * DD + c4);
            float* a = &av.x;
            float* p = &pv.x;
            #pragma unroll
            for (int j = 0; j < 4; ++j) {
                int col = c4 + j;
                float mean = stats[ka * 128 + col] * (1.0f / NN);
                float m2 = stats[ka * 128 + 64 + col] * (1.0f / NN);
                float inv = rsqrtf(m2 - mean * mean + BN_EPS);
                float xn = gamma[col] * (a[j] - mean) * inv + beta[col];
                p[j] += (xn >= 0.f) ? xn : NEG * xn;
            }
            if (mode == 1) *(f4*)(e1 + kabase + (size_t)row * DD + c4) = pv;
        }
        f4 rv = *(const f4*)(rels + ka * 64 + c4);
        xl[rl][c4 + 0] = pv.x * rv.x;
        xl[rl][c4 + 1] = pv.y * rv.y;
        xl[rl][c4 + 2] = pv.z * rv.z;
        xl[rl][c4 + 3] = pv.w * rv.w;
    }
    __syncthreads();
    float ax = 0.f, ay = 0.f, az = 0.f, aw = 0.f;
    #pragma unroll
    for (int kk = 0; kk < 64; ++kk) {
        float xv = xl[rl][kk];
        const float* wrow = Wl + kk * 64 + c4;
        ax += xv * wrow[0];
        ay += xv * wrow[1];
        az += xv * wrow[2];
        aw += xv * wrow[3];
    }
    ushort4 o;
    o.x = f2b(ax); o.y = f2b(ay); o.z = f2b(az); o.w = f2b(aw);
    *(ushort4*)(h_bf + kabase + (size_t)row * DD + c4) = o;
}

// ---- mega: bin edges (blocks 0..195) || layer-0 GEMM (196..12695) ----
__global__ __launch_bounds__(256) void k_bin_gemm0(
    const int* __restrict__ e0, const int* __restrict__ e1,
    const int* __restrict__ e2, const int* __restrict__ e3,
    int* __restrict__ gcur, unsigned* __restrict__ bin,
    const float* __restrict__ feat, const float* __restrict__ rels,
    const float* __restrict__ W, unsigned short* __restrict__ h_bf) {
    __shared__ float Wl[4096];
    __shared__ float xl[16][68];
    __shared__ int hist[NBK];
    __shared__ int myb[NBK];
    int tid = threadIdx.x;
    int bx = blockIdx.x;
    if (bx < 196) {
        int k = bx / NCHK, cb = bx - k * NCHK;
        const int* ed = esel(k, e0, e1, e2, e3);
        int lo = cb * CHUNK, hi = min(EE, lo + CHUNK);
        for (int i = tid; i < NBK; i += 256) hist[i] = 0;
        __syncthreads();
        for (int i = lo + tid; i < hi; i += 256)
            atomicAdd(&hist[(k * NN + ed[EE + i]) >> 7], 1);
        __syncthreads();
        for (int i = tid; i < NBK; i += 256) {
            int c = hist[i];
            myb[i] = c ? atomicAdd(&gcur[i], c) : 0;
            hist[i] = 0;          // reuse as local cursor
        }
        __syncthreads();
        for (int i = lo + tid; i < hi; i += 256) {
            int src = ed[i], dst = ed[EE + i];
            int f = k * NN + dst, b = f >> 7;
            int p = atomicAdd(&hist[b], 1);
            bin[myb[b] + p] = ((unsigned)(f & 127) << 18) | (unsigned)(k * NN + src);
        }
    } else {
        gemm_body(Wl, xl, bx - 196, tid, feat, (size_t)0,
                  nullptr, nullptr, nullptr, nullptr, rels, W,
                  nullptr, h_bf, 0);
    }
}

// ---- per-bucket degree -> dinv ----
__global__ __launch_bounds__(256) void k_degdinv(
    const unsigned* __restrict__ bin, const int* __restrict__ gbase,
    float* __restrict__ dinv) {
    __shared__ int cnt[BROW];
    int tid = threadIdx.x, b = blockIdx.x;
    if (tid < BROW) cnt[tid] = 0;
    __syncthreads();
    int s0 = gbase[b], s1 = gbase[b + 1];
    for (int i = s0 + tid; i < s1; i += 256)
        atomicAdd(&cnt[bin[i] >> 18], 1);
    __syncthreads();
    int f = b * BROW + tid;
    if (tid < BROW && f < NF) dinv[f] = rsqrtf((float)(cnt[tid] + 1));
}

// ---- standalone GEMM (layers 1,2) ----
__global__ __launch_bounds__(256) void k_gemm(
    const float* __restrict__ prevbuf, size_t prev_ka_stride,
    const float* __restrict__ agg, const float* __restrict__ stats,
    const float* __restrict__ gamma, const float* __restrict__ beta,
    const float* __restrict__ rels, const float* __restrict__ W,
    float* __restrict__ e1, unsigned short* __restrict__ h_bf, int mode) {
    __shared__ float Wl[4096];
    __shared__ float xl[16][68];
    gemm_body(Wl, xl, blockIdx.y * 3125 + blockIdx.x, threadIdx.x,
              prevbuf, prev_ka_stride, agg, stats, gamma, beta,
              rels, W, e1, h_bf, mode);
}

// ---- gather: block = 1 bucket (128 dsts); LDS f32 accumulation ----
__global__ __launch_bounds__(256) void k_gather2(
    const unsigned short* __restrict__ h_bf, const unsigned* __restrict__ bin,
    const int* __restrict__ gbase, const float* __restrict__ dinv,
    const float* __restrict__ bias, float* __restrict__ dstbuf) {
    __shared__ float acc[BROW][66];
    __shared__ unsigned st[STCAP];
    __shared__ float dloc[BROW];
    int tid = threadIdx.x, b = blockIdx.x;
    int fl0 = b * BROW;
    for (int i = tid; i < BROW * 66; i += 256) ((float*)acc)[i] = 0.f;
    if (tid < BROW) {
        int f = fl0 + tid;
        dloc[tid] = (f < NF) ? dinv[f] : 0.f;
    }
    int s0 = gbase[b], s1 = gbase[b + 1];
    int lane = tid & 63, w = tid >> 6;
    int g = lane >> 3, c8 = lane & 7;
    int estream = w * 8 + g;               // 0..31 edge streams
    for (int chunk = s0; chunk < s1; chunk += STCAP) {
        int n = min(STCAP, s1 - chunk);
        __syncthreads();                   // acc zeroed / prev chunk consumed
        for (int i = tid; i < n; i += 256) st[i] = bin[chunk + i];
        __syncthreads();
        for (int e = estream; e < n; e += 32) {
            unsigned u = st[e];
            int dl = u >> 18;
            int fs = u & 0x3ffff;
            float nm = dinv[fs] * dloc[dl];
            uint4 hv = *(const uint4*)(h_bf + (size_t)fs * DD + c8 * 8);
            float* ar = &acc[dl][c8 * 8];
            atomicAdd(ar + 0, __uint_as_float(hv.x << 16) * nm);
            atomicAdd(ar + 1, __uint_as_float(hv.x & 0xffff0000u) * nm);
            atomicAdd(ar + 2, __uint_as_float(hv.y << 16) * nm);
            atomicAdd(ar + 3, __uint_as_float(hv.y & 0xffff0000u) * nm);
            atomicAdd(ar + 4, __uint_as_float(hv.z << 16) * nm);
            atomicAdd(ar + 5, __uint_as_float(hv.z & 0xffff0000u) * nm);
            atomicAdd(ar + 6, __uint_as_float(hv.w << 16) * nm);
            atomicAdd(ar + 7, __uint_as_float(hv.w & 0xffff0000u) * nm);
        }
    }
    __syncthreads();
    // epilogue: agg = bias + selfloop + acc  (4 rows per pass, lane = col)
    for (int r = w; r < BROW; r += 4) {
        int f = fl0 + r;
        if (f < NF) {
            float di = dloc[r], d2 = di * di;
            float v = bias[lane] + b2f(h_bf[(size_t)f * DD + lane]) * d2 + acc[r][lane];
            dstbuf[(size_t)f * DD + lane] = v;
        }
    }
}

// ---- BN column stats (sum, sumsq) ----
__global__ __launch_bounds__(256) void k_bnstats(
    const float* __restrict__ agg, float* __restrict__ stats) {
    int ka = blockIdx.y;
    int col = threadIdx.x & 63;
    int w = threadIdx.x >> 6;
    long r0 = (long)blockIdx.x * 256 + w * 64;
    float s = 0.f, s2 = 0.f;
    size_t base = (size_t)ka * NN * DD;
    for (int i = 0; i < 64; ++i) {
        long r = r0 + i;
        if (r < NN) {
            float v = agg[base + r * DD + col];
            s += v;
            s2 += v * v;
        }
    }
    atomicAdd(stats + ka * 128 + col, s);
    atomicAdd(stats + ka * 128 + 64 + col, s2);
}

extern "C" void kernel_launch(void* const* d_in, const int* in_sizes, int n_in,
                              void* d_out, int out_size, void* d_ws, size_t ws_size,
                              hipStream_t stream) {
    const float* feat = (const float*)d_in[0];
    const float* poir = (const float*)d_in[1];
    const float* sr   = (const float*)d_in[2];
    const float* dr   = (const float*)d_in[3];
    const float* nr   = (const float*)d_in[4];
    const int* e_poi  = (const int*)d_in[5];
    const int* e_s    = (const int*)d_in[6];
    const int* e_d    = (const int*)d_in[7];
    const int* e_n    = (const int*)d_in[8];
    const float* gcnW = (const float*)d_in[9];
    const float* gcnb = (const float*)d_in[10];
    const float* bng  = (const float*)d_in[11];
    const float* bnb  = (const float*)d_in[12];
    const float* relW = (const float*)d_in[13];
    const float* relb = (const float*)d_in[14];

    float* out = (float*)d_out;
    float* rel_out = out + (size_t)4 * NN * DD;
    float* ws = (float*)d_ws;

    size_t o = 0;
    auto alloc = [&](size_t words) { o = (o + 3) & ~(size_t)3; size_t r = o; o += words; return r; };
    float* dinv     = ws + alloc(NF);
    float* rels_all = ws + alloc(1024);
    float* stats    = ws + alloc(1024);                    // [2 layers][512]
    int*   ghist    = (int*)(ws + alloc(NBK));
    int*   gbase    = (int*)(ws + alloc(NBK + 1));
    int*   gcur     = (int*)(ws + alloc(NBK));
    unsigned* bin   = (unsigned*)(ws + alloc((size_t)4 * EE));
    unsigned short* h_bf = (unsigned short*)(ws + alloc((size_t)2 * NN * DD));
    float* agg      = ws + alloc((size_t)4 * NN * DD);
    float* e1       = ws + alloc((size_t)4 * NN * DD);

    const int* E0 = e_n;  const int* E1 = e_poi;
    const int* E2 = e_s;  const int* E3 = e_d;

    hipMemsetAsync(ghist, 0, NBK * sizeof(int), stream);
    k_hist_rels<<<197, 256, 0, stream>>>(E0, E1, E2, E3, ghist,
                                         nr, poir, sr, dr, relW, relb,
                                         rels_all, rel_out, stats);
    k_scanbk<<<1, 256, 0, stream>>>(ghist, gbase, gcur);
    k_bin_gemm0<<<12696, 256, 0, stream>>>(E0, E1, E2, E3, gcur, bin,
                                           feat, rels_all + 0, gcnW + 0, h_bf);
    k_degdinv<<<NBK, 256, 0, stream>>>(bin, gbase, dinv);

    // layer 0
    k_gather2<<<NBK, 256, 0, stream>>>(h_bf, bin, gbase, dinv, gcnb + 0, agg);
    k_bnstats<<<dim3(196, 4), 256, 0, stream>>>(agg, stats + 0);

    // layer 1
    k_gemm<<<dim3(3125, 4), 256, 0, stream>>>(
        feat, (size_t)0, agg, stats + 0, bng + 0, bnb + 0,
        rels_all + 256, gcnW + 4096, e1, h_bf, 1);
    k_gather2<<<NBK, 256, 0, stream>>>(h_bf, bin, gbase, dinv, gcnb + 64, agg);
    k_bnstats<<<dim3(196, 4), 256, 0, stream>>>(agg, stats + 512);

    // layer 2
    k_gemm<<<dim3(3125, 4), 256, 0, stream>>>(
        e1, (size_t)(NN * DD), agg, stats + 512, bng + 64, bnb + 64,
        rels_all + 512, gcnW + 8192, nullptr, h_bf, 2);
    k_gather2<<<NBK, 256, 0, stream>>>(h_bf, bin, gbase, dinv, gcnb + 128, out);
}

// Round 11
// 685.346 us; speedup vs baseline: 5.6865x; 5.6865x over previous
//
#include <hip/hip_runtime.h>

#define NN 50000
#define DD 64
#define EE 800000
#define NF 200000            // 4*NN flat nodes
#define BROW 128             // dst nodes per bucket
#define NBK 1563             // ceil(NF/BROW)
#define NCHK 49              // bin blocks per relation
#define CHUNK 16384
#define BN_EPS 1e-5f
#define NEG 0.01f

typedef float4 f4;

__device__ __forceinline__ float b2f(unsigned short u) {
    return __uint_as_float(((unsigned)u) << 16);
}
__device__ __forceinline__ unsigned short f2b(float x) {
    unsigned u = __float_as_uint(x);
    u += 0x7fffu + ((u >> 16) & 1u);   // RNE
    return (unsigned short)(u >> 16);
}

__device__ __forceinline__ const int* esel(int k, const int* e0, const int* e1,
                                           const int* e2, const int* e3) {
    return (k == 0) ? e0 : (k == 1) ? e1 : (k == 2) ? e2 : e3;
}

// ---- bucket histogram (blocks 0..195) + rels/stats-zero (block 196) ----
__global__ __launch_bounds__(256) void k_hist_rels(
    const int* __restrict__ e0, const int* __restrict__ e1,
    const int* __restrict__ e2, const int* __restrict__ e3,
    int* __restrict__ ghist,
    const float* __restrict__ nr, const float* __restrict__ poir,
    const float* __restrict__ sr, const float* __restrict__ dr,
    const float* __restrict__ relW, const float* __restrict__ relb,
    float* __restrict__ rels_all, float* __restrict__ rel_out,
    float* __restrict__ stats) {
    int tid = threadIdx.x;
    if (blockIdx.x < 196) {
        __shared__ int hist[NBK];
        int k = blockIdx.x / NCHK;
        int cb = blockIdx.x - k * NCHK;
        const int* ed = esel(k, e0, e1, e2, e3);
        int lo = cb * CHUNK, hi = min(EE, lo + CHUNK);
        for (int i = tid; i < NBK; i += 256) hist[i] = 0;
        __syncthreads();
        for (int i = lo + tid; i < hi; i += 256)
            atomicAdd(&hist[(k * NN + ed[EE + i]) >> 7], 1);
        __syncthreads();
        for (int i = tid; i < NBK; i += 256) {
            int c = hist[i];
            if (c) atomicAdd(&ghist[i], c);
        }
    } else {
        __shared__ float cur[4][64];
        stats[tid] = 0.f; stats[tid + 256] = 0.f;
        stats[tid + 512] = 0.f; stats[tid + 768] = 0.f;
        int k = tid >> 6, j = tid & 63;
        const float* r0 = (k == 0) ? nr : (k == 1) ? poir : (k == 2) ? sr : dr;
        float v = r0[j];
        cur[k][j] = v;
        rels_all[(0 * 4 + k) * 64 + j] = v;
        __syncthreads();
        for (int s = 0; s < 3; ++s) {
            const float* W = relW + s * 4096;
            float acc = relb[s * 64 + j];
            #pragma unroll 8
            for (int kk = 0; kk < 64; ++kk) acc += cur[k][kk] * W[j * 64 + kk];
            __syncthreads();
            cur[k][j] = acc;
            rels_all[((s + 1) * 4 + k) * 64 + j] = acc;
            __syncthreads();
        }
        rel_out[k * 64 + j] = cur[k][j];
    }
}

// ---- exclusive scan of 1563 bucket counts -> gbase (+sentinel), gcur ----
__global__ __launch_bounds__(256) void k_scanbk(const int* __restrict__ ghist,
                                                int* __restrict__ gbase,
                                                int* __restrict__ gcur) {
    __shared__ int s[256];
    __shared__ int carry;
    int tid = threadIdx.x;
    if (tid == 0) carry = 0;
    __syncthreads();
    for (int base = 0; base < NBK; base += 256) {
        int i = base + tid;
        int v = (i < NBK) ? ghist[i] : 0;
        s[tid] = v;
        __syncthreads();
        for (int d = 1; d < 256; d <<= 1) {
            int t = (tid >= d) ? s[tid - d] : 0;
            __syncthreads();
            s[tid] += t;
            __syncthreads();
        }
        int c = carry;
        if (i < NBK) { gbase[i] = s[tid] - v + c; gcur[i] = s[tid] - v + c; }
        __syncthreads();
        if (tid == 0) carry = c + s[255];
        __syncthreads();
    }
    if (tid == 0) gbase[NBK] = carry;   // = 4*EE
}

// ---- shared GEMM body: [optional BN+leaky+residual] then h_bf = (e.*rel)@W ----
__device__ __forceinline__ void gemm_body(
    float* __restrict__ Wl, float (*__restrict__ xl)[68], int bxl, int tid,
    const float* __restrict__ prevbuf, size_t prev_ka_stride,
    const float* __restrict__ agg, const float* __restrict__ stats,
    const float* __restrict__ gamma, const float* __restrict__ beta,
    const float* __restrict__ rels, const float* __restrict__ W,
    float* __restrict__ e1, unsigned short* __restrict__ h_bf, int mode) {
    int ka = bxl / 3125;
    int row0 = (bxl - ka * 3125) * 16;
    {
        const f4* W4 = (const f4*)W;
        f4* Wl4 = (f4*)Wl;
        Wl4[tid] = W4[tid];
        Wl4[tid + 256] = W4[tid + 256];
        Wl4[tid + 512] = W4[tid + 512];
        Wl4[tid + 768] = W4[tid + 768];
    }
    int rl = tid >> 4, c4 = (tid & 15) * 4;
    int row = row0 + rl;
    size_t kabase = (size_t)ka * NN * DD;
    {
        f4 pv = *(const f4*)(prevbuf + (size_t)ka * prev_ka_stride + (size_t)row * DD + c4);
        if (mode > 0) {
            f4 av = *(const f4*)(agg + kabase + (size_t)row * DD + c4);
            float* a = &av.x;
            float* p = &pv.x;
            #pragma unroll
            for (int j = 0; j < 4; ++j) {
                int col = c4 + j;
                float mean = stats[ka * 128 + col] * (1.0f / NN);
                float m2 = stats[ka * 128 + 64 + col] * (1.0f / NN);
                float inv = rsqrtf(m2 - mean * mean + BN_EPS);
                float xn = gamma[col] * (a[j] - mean) * inv + beta[col];
                p[j] += (xn >= 0.f) ? xn : NEG * xn;
            }
            if (mode == 1) *(f4*)(e1 + kabase + (size_t)row * DD + c4) = pv;
        }
        f4 rv = *(const f4*)(rels + ka * 64 + c4);
        xl[rl][c4 + 0] = pv.x * rv.x;
        xl[rl][c4 + 1] = pv.y * rv.y;
        xl[rl][c4 + 2] = pv.z * rv.z;
        xl[rl][c4 + 3] = pv.w * rv.w;
    }
    __syncthreads();
    float ax = 0.f, ay = 0.f, az = 0.f, aw = 0.f;
    #pragma unroll
    for (int kk = 0; kk < 64; ++kk) {
        float xv = xl[rl][kk];
        const float* wrow = Wl + kk * 64 + c4;
        ax += xv * wrow[0];
        ay += xv * wrow[1];
        az += xv * wrow[2];
        aw += xv * wrow[3];
    }
    ushort4 o;
    o.x = f2b(ax); o.y = f2b(ay); o.z = f2b(az); o.w = f2b(aw);
    *(ushort4*)(h_bf + kabase + (size_t)row * DD + c4) = o;
}

// ---- mega: bin edges (blocks 0..195, LDS aliased) || layer-0 GEMM (196..12695) ----
__global__ __launch_bounds__(256) void k_bin_gemm0(
    const int* __restrict__ e0, const int* __restrict__ e1,
    const int* __restrict__ e2, const int* __restrict__ e3,
    int* __restrict__ gcur, unsigned* __restrict__ bin,
    const float* __restrict__ feat, const float* __restrict__ rels,
    const float* __restrict__ W, unsigned short* __restrict__ h_bf) {
    __shared__ float shmem[5184];        // Wl[4096]+xl[16][68]  ||  hist[NBK]+myb[NBK]
    int tid = threadIdx.x;
    int bx = blockIdx.x;
    if (bx < 196) {
        int* hist = (int*)shmem;
        int* myb  = (int*)shmem + NBK;
        int k = bx / NCHK, cb = bx - k * NCHK;
        const int* ed = esel(k, e0, e1, e2, e3);
        int lo = cb * CHUNK, hi = min(EE, lo + CHUNK);
        for (int i = tid; i < NBK; i += 256) hist[i] = 0;
        __syncthreads();
        for (int i = lo + tid; i < hi; i += 256)
            atomicAdd(&hist[(k * NN + ed[EE + i]) >> 7], 1);
        __syncthreads();
        for (int i = tid; i < NBK; i += 256) {
            int c = hist[i];
            myb[i] = c ? atomicAdd(&gcur[i], c) : 0;
            hist[i] = 0;          // reuse as local cursor
        }
        __syncthreads();
        for (int i = lo + tid; i < hi; i += 256) {
            int src = ed[i], dst = ed[EE + i];
            int f = k * NN + dst, b = f >> 7;
            int p = atomicAdd(&hist[b], 1);
            bin[myb[b] + p] = ((unsigned)(f & 127) << 18) | (unsigned)(k * NN + src);
        }
    } else {
        float* Wl = shmem;
        float (*xl)[68] = (float(*)[68])(shmem + 4096);
        gemm_body(Wl, xl, bx - 196, tid, feat, (size_t)0,
                  nullptr, nullptr, nullptr, nullptr, rels, W,
                  nullptr, h_bf, 0);
    }
}

// ---- per-bucket finish: bin -> exact CSR + off + dinv ----
__global__ __launch_bounds__(256) void k_fine(
    const unsigned* __restrict__ bin, const int* __restrict__ gbase,
    int* __restrict__ off, float* __restrict__ dinv, int* __restrict__ csr) {
    __shared__ int cnt[BROW], noff[BROW], curl[BROW];
    __shared__ int wsum;
    int tid = threadIdx.x, b = blockIdx.x;
    if (tid < BROW) cnt[tid] = 0;
    __syncthreads();
    int s0 = gbase[b], s1 = gbase[b + 1];
    for (int i = s0 + tid; i < s1; i += 256)
        atomicAdd(&cnt[bin[i] >> 18], 1);
    __syncthreads();
    int c0 = (tid < BROW) ? cnt[tid] : 0;
    int c = c0;
    #pragma unroll
    for (int d = 1; d < 64; d <<= 1) {
        int t = __shfl_up(c, d, 64);
        if ((tid & 63) >= d) c += t;
    }
    if (tid == 63) wsum = c;               // total of wave 0 (dsts 0..63)
    __syncthreads();
    if (tid < BROW) {
        int ex = c - c0 + ((tid >= 64) ? wsum : 0);   // exclusive within bucket
        noff[tid] = s0 + ex;
        curl[tid] = 0;
        int f = b * BROW + tid;
        if (f < NF) {
            off[f] = s0 + ex;
            dinv[f] = rsqrtf((float)(c0 + 1));
        }
    }
    __syncthreads();
    for (int i = s0 + tid; i < s1; i += 256) {
        unsigned u = bin[i];
        int dl = u >> 18;
        int p = atomicAdd(&curl[dl], 1);
        csr[noff[dl] + p] = (int)(u & 0x3ffff);
    }
    if (b == 0 && tid == 0) off[NF] = 4 * EE;
}

// ---- standalone GEMM (layers 1,2) ----
__global__ __launch_bounds__(256) void k_gemm(
    const float* __restrict__ prevbuf, size_t prev_ka_stride,
    const float* __restrict__ agg, const float* __restrict__ stats,
    const float* __restrict__ gamma, const float* __restrict__ beta,
    const float* __restrict__ rels, const float* __restrict__ W,
    float* __restrict__ e1, unsigned short* __restrict__ h_bf, int mode) {
    __shared__ float Wl[4096];
    __shared__ float xl[16][68];
    gemm_body(Wl, xl, blockIdx.y * 3125 + blockIdx.x, threadIdx.x,
              prevbuf, prev_ka_stride, agg, stats, gamma, beta,
              rels, W, e1, h_bf, mode);
}

// ---- gather: wave = 1 dst node; lane = (edge-group g of 8, col-chunk c8 of 8) ----
__global__ __launch_bounds__(256) void k_gather(
    const unsigned short* __restrict__ h_bf, const int* __restrict__ csr,
    const int* __restrict__ off, const float* __restrict__ dinv,
    const float* __restrict__ bias, float* __restrict__ dstbuf) {
    int tid = threadIdx.x;
    int lane = tid & 63, w = tid >> 6;
    int v = blockIdx.x * 4 + w;               // flat node id (relation-major)
    int g = lane >> 3, c8 = lane & 7;
    int s0 = off[v], s1 = off[v + 1];
    float di = dinv[v];
    float a0 = 0.f, a1 = 0.f, a2 = 0.f, a3 = 0.f;
    float a4 = 0.f, a5 = 0.f, a6 = 0.f, a7 = 0.f;
    const unsigned short* hcol = h_bf + c8 * 8;
    #pragma unroll 2
    for (int i = s0 + g; i < s1; i += 8) {
        int sf = csr[i];
        float nm = dinv[sf] * di;
        uint4 hv = *(const uint4*)(hcol + (size_t)sf * DD);
        a0 += __uint_as_float(hv.x << 16) * nm;
        a1 += __uint_as_float(hv.x & 0xffff0000u) * nm;
        a2 += __uint_as_float(hv.y << 16) * nm;
        a3 += __uint_as_float(hv.y & 0xffff0000u) * nm;
        a4 += __uint_as_float(hv.z << 16) * nm;
        a5 += __uint_as_float(hv.z & 0xffff0000u) * nm;
        a6 += __uint_as_float(hv.w << 16) * nm;
        a7 += __uint_as_float(hv.w & 0xffff0000u) * nm;
    }
    #pragma unroll
    for (int m = 8; m <= 32; m <<= 1) {
        a0 += __shfl_xor(a0, m); a1 += __shfl_xor(a1, m);
        a2 += __shfl_xor(a2, m); a3 += __shfl_xor(a3, m);
        a4 += __shfl_xor(a4, m); a5 += __shfl_xor(a5, m);
        a6 += __shfl_xor(a6, m); a7 += __shfl_xor(a7, m);
    }
    if (lane < 8) {
        float d2 = di * di;
        uint4 hd = *(const uint4*)(h_bf + (size_t)v * DD + lane * 8);
        f4 b0 = *(const f4*)(bias + lane * 8);
        f4 b1 = *(const f4*)(bias + lane * 8 + 4);
        f4 o0, o1;
        o0.x = b0.x + __uint_as_float(hd.x << 16) * d2 + a0;
        o0.y = b0.y + __uint_as_float(hd.x & 0xffff0000u) * d2 + a1;
        o0.z = b0.z + __uint_as_float(hd.y << 16) * d2 + a2;
        o0.w = b0.w + __uint_as_float(hd.y & 0xffff0000u) * d2 + a3;
        o1.x = b1.x + __uint_as_float(hd.z << 16) * d2 + a4;
        o1.y = b1.y + __uint_as_float(hd.z & 0xffff0000u) * d2 + a5;
        o1.z = b1.z + __uint_as_float(hd.w << 16) * d2 + a6;
        o1.w = b1.w + __uint_as_float(hd.w & 0xffff0000u) * d2 + a7;
        *(f4*)(dstbuf + (size_t)v * DD + lane * 8) = o0;
        *(f4*)(dstbuf + (size_t)v * DD + lane * 8 + 4) = o1;
    }
}

// ---- BN column stats (sum, sumsq) ----
__global__ __launch_bounds__(256) void k_bnstats(
    const float* __restrict__ agg, float* __restrict__ stats) {
    int ka = blockIdx.y;
    int col = threadIdx.x & 63;
    int w = threadIdx.x >> 6;
    long r0 = (long)blockIdx.x * 256 + w * 64;
    float s = 0.f, s2 = 0.f;
    size_t base = (size_t)ka * NN * DD;
    for (int i = 0; i < 64; ++i) {
        long r = r0 + i;
        if (r < NN) {
            float v = agg[base + r * DD + col];
            s += v;
            s2 += v * v;
        }
    }
    atomicAdd(stats + ka * 128 + col, s);
    atomicAdd(stats + ka * 128 + 64 + col, s2);
}

extern "C" void kernel_launch(void* const* d_in, const int* in_sizes, int n_in,
                              void* d_out, int out_size, void* d_ws, size_t ws_size,
                              hipStream_t stream) {
    const float* feat = (const float*)d_in[0];
    const float* poir = (const float*)d_in[1];
    const float* sr   = (const float*)d_in[2];
    const float* dr   = (const float*)d_in[3];
    const float* nr   = (const float*)d_in[4];
    const int* e_poi  = (const int*)d_in[5];
    const int* e_s    = (const int*)d_in[6];
    const int* e_d    = (const int*)d_in[7];
    const int* e_n    = (const int*)d_in[8];
    const float* gcnW = (const float*)d_in[9];
    const float* gcnb = (const float*)d_in[10];
    const float* bng  = (const float*)d_in[11];
    const float* bnb  = (const float*)d_in[12];
    const float* relW = (const float*)d_in[13];
    const float* relb = (const float*)d_in[14];

    float* out = (float*)d_out;
    float* rel_out = out + (size_t)4 * NN * DD;
    float* ws = (float*)d_ws;

    size_t o = 0;
    auto alloc = [&](size_t words) { o = (o + 3) & ~(size_t)3; size_t r = o; o += words; return r; };
    float* dinv     = ws + alloc(NF);
    float* rels_all = ws + alloc(1024);
    float* stats    = ws + alloc(1024);                    // [2 layers][512]
    int*   ghist    = (int*)(ws + alloc(NBK));
    int*   gbase    = (int*)(ws + alloc(NBK + 1));
    int*   gcur     = (int*)(ws + alloc(NBK));
    int*   off      = (int*)(ws + alloc(NF + 1));
    unsigned* bin   = (unsigned*)(ws + alloc((size_t)4 * EE));
    int*   csr      = (int*)(ws + alloc((size_t)4 * EE));
    unsigned short* h_bf = (unsigned short*)(ws + alloc((size_t)2 * NN * DD));
    float* agg      = ws + alloc((size_t)4 * NN * DD);
    float* e1       = ws + alloc((size_t)4 * NN * DD);

    const int* E0 = e_n;  const int* E1 = e_poi;
    const int* E2 = e_s;  const int* E3 = e_d;

    hipMemsetAsync(ghist, 0, NBK * sizeof(int), stream);
    k_hist_rels<<<197, 256, 0, stream>>>(E0, E1, E2, E3, ghist,
                                         nr, poir, sr, dr, relW, relb,
                                         rels_all, rel_out, stats);
    k_scanbk<<<1, 256, 0, stream>>>(ghist, gbase, gcur);
    k_bin_gemm0<<<12696, 256, 0, stream>>>(E0, E1, E2, E3, gcur, bin,
                                           feat, rels_all + 0, gcnW + 0, h_bf);
    k_fine<<<NBK, 256, 0, stream>>>(bin, gbase, off, dinv, csr);

    // layer 0
    k_gather<<<50000, 256, 0, stream>>>(h_bf, csr, off, dinv, gcnb + 0, agg);
    k_bnstats<<<dim3(196, 4), 256, 0, stream>>>(agg, stats + 0);

    // layer 1
    k_gemm<<<dim3(3125, 4), 256, 0, stream>>>(
        feat, (size_t)0, agg, stats + 0, bng + 0, bnb + 0,
        rels_all + 256, gcnW + 4096, e1, h_bf, 1);
    k_gather<<<50000, 256, 0, stream>>>(h_bf, csr, off, dinv, gcnb + 64, agg);
    k_bnstats<<<dim3(196, 4), 256, 0, stream>>>(agg, stats + 512);

    // layer 2
    k_gemm<<<dim3(3125, 4), 256, 0, stream>>>(
        e1, (size_t)(NN * DD), agg, stats + 512, bng + 64, bnb + 64,
        rels_all + 512, gcnW + 8192, nullptr, h_bf, 2);
    k_gather<<<50000, 256, 0, stream>>>(h_bf, csr, off, dinv, gcnb + 128, out);
}

// Round 13
// 666.874 us; speedup vs baseline: 5.8441x; 1.0277x over previous
//
#include <hip/hip_runtime.h>

#define NN 50000
#define DD 64
#define EE 800000
#define NF 200000            // 4*NN flat nodes
#define BROW 128             // dst nodes per bucket
#define NBK 1563             // ceil(NF/BROW)
#define CAP 3072             // padded bucket window (max expected fill ~2300)
#define NCHK 49              // bin blocks per relation
#define CHUNK 16384
#define BN_EPS 1e-5f
#define NEG 0.01f

typedef float4 f4;

__device__ __forceinline__ float b2f(unsigned short u) {
    return __uint_as_float(((unsigned)u) << 16);
}
__device__ __forceinline__ unsigned short f2b(float x) {
    unsigned u = __float_as_uint(x);
    u += 0x7fffu + ((u >> 16) & 1u);   // RNE
    return (unsigned short)(u >> 16);
}

__device__ __forceinline__ const int* esel(int k, const int* e0, const int* e1,
                                           const int* e2, const int* e3) {
    return (k == 0) ? e0 : (k == 1) ? e1 : (k == 2) ? e2 : e3;
}

// ---- init: gcur[b]=b*CAP (blocks 0..6), stats zero (block 7), rels (block 8) ----
__global__ __launch_bounds__(256) void k_init(
    int* __restrict__ gcur, float* __restrict__ stats,
    const float* __restrict__ nr, const float* __restrict__ poir,
    const float* __restrict__ sr, const float* __restrict__ dr,
    const float* __restrict__ relW, const float* __restrict__ relb,
    float* __restrict__ rels_all, float* __restrict__ rel_out) {
    int tid = threadIdx.x;
    int bx = blockIdx.x;
    if (bx < 7) {
        int i = bx * 256 + tid;
        if (i < NBK) gcur[i] = i * CAP;
    } else if (bx == 7) {
        stats[tid] = 0.f; stats[tid + 256] = 0.f;
        stats[tid + 512] = 0.f; stats[tid + 768] = 0.f;
    } else {
        __shared__ float cur[4][64];
        int k = tid >> 6, j = tid & 63;
        const float* r0 = (k == 0) ? nr : (k == 1) ? poir : (k == 2) ? sr : dr;
        float v = r0[j];
        cur[k][j] = v;
        rels_all[(0 * 4 + k) * 64 + j] = v;
        __syncthreads();
        for (int s = 0; s < 3; ++s) {
            const float* W = relW + s * 4096;
            float acc = relb[s * 64 + j];
            #pragma unroll 8
            for (int kk = 0; kk < 64; ++kk) acc += cur[k][kk] * W[j * 64 + kk];
            __syncthreads();
            cur[k][j] = acc;
            rels_all[((s + 1) * 4 + k) * 64 + j] = acc;
            __syncthreads();
        }
        rel_out[k * 64 + j] = cur[k][j];
    }
}

// ---- shared GEMM body: [optional BN+leaky+residual] then h_bf = (e.*rel)@W ----
// mode 0: prev=feat, no BN.  mode 1: prev=feat, BN(bf16 agg), write e1.
// mode 2: prev=e1, BN(bf16 agg), no write.
__device__ __forceinline__ void gemm_body(
    float* __restrict__ Wl, float (*__restrict__ xl)[68], int bxl, int tid,
    const float* __restrict__ prevbuf, size_t prev_ka_stride,
    const unsigned short* __restrict__ aggb, const float* __restrict__ stats,
    const float* __restrict__ gamma, const float* __restrict__ beta,
    const float* __restrict__ rels, const float* __restrict__ W,
    float* __restrict__ e1, unsigned short* __restrict__ h_bf, int mode) {
    int ka = bxl / 3125;
    int row0 = (bxl - ka * 3125) * 16;
    {
        const f4* W4 = (const f4*)W;
        f4* Wl4 = (f4*)Wl;
        Wl4[tid] = W4[tid];
        Wl4[tid + 256] = W4[tid + 256];
        Wl4[tid + 512] = W4[tid + 512];
        Wl4[tid + 768] = W4[tid + 768];
    }
    int rl = tid >> 4, c4 = (tid & 15) * 4;
    int row = row0 + rl;
    size_t kabase = (size_t)ka * NN * DD;
    {
        f4 pv = *(const f4*)(prevbuf + (size_t)ka * prev_ka_stride + (size_t)row * DD + c4);
        if (mode > 0) {
            ushort4 av = *(const ushort4*)(aggb + kabase + (size_t)row * DD + c4);
            float a[4] = {b2f(av.x), b2f(av.y), b2f(av.z), b2f(av.w)};
            float* p = &pv.x;
            #pragma unroll
            for (int j = 0; j < 4; ++j) {
                int col = c4 + j;
                float mean = stats[ka * 128 + col] * (1.0f / NN);
                float m2 = stats[ka * 128 + 64 + col] * (1.0f / NN);
                float inv = rsqrtf(m2 - mean * mean + BN_EPS);
                float xn = gamma[col] * (a[j] - mean) * inv + beta[col];
                p[j] += (xn >= 0.f) ? xn : NEG * xn;
            }
            if (mode == 1) *(f4*)(e1 + kabase + (size_t)row * DD + c4) = pv;
        }
        f4 rv = *(const f4*)(rels + ka * 64 + c4);
        xl[rl][c4 + 0] = pv.x * rv.x;
        xl[rl][c4 + 1] = pv.y * rv.y;
        xl[rl][c4 + 2] = pv.z * rv.z;
        xl[rl][c4 + 3] = pv.w * rv.w;
    }
    __syncthreads();
    float ax = 0.f, ay = 0.f, az = 0.f, aw = 0.f;
    #pragma unroll
    for (int kk = 0; kk < 64; ++kk) {
        float xv = xl[rl][kk];
        const float* wrow = Wl + kk * 64 + c4;
        ax += xv * wrow[0];
        ay += xv * wrow[1];
        az += xv * wrow[2];
        aw += xv * wrow[3];
    }
    ushort4 o;
    o.x = f2b(ax); o.y = f2b(ay); o.z = f2b(az); o.w = f2b(aw);
    *(ushort4*)(h_bf + kabase + (size_t)row * DD + c4) = o;
}

// ---- mega: bin edges (blocks 0..195, fixed-cap windows) || layer-0 GEMM ----
__global__ __launch_bounds__(256) void k_bin_gemm0(
    const int* __restrict__ e0, const int* __restrict__ e1,
    const int* __restrict__ e2, const int* __restrict__ e3,
    int* __restrict__ gcur, unsigned* __restrict__ bin,
    const float* __restrict__ feat, const float* __restrict__ rels,
    const float* __restrict__ W, unsigned short* __restrict__ h_bf) {
    __shared__ float shmem[5184];        // Wl[4096]+xl[16][68]  ||  hist[NBK]+myb[NBK]
    int tid = threadIdx.x;
    int bx = blockIdx.x;
    if (bx < 196) {
        int* hist = (int*)shmem;
        int* myb  = (int*)shmem + NBK;
        int k = bx / NCHK, cb = bx - k * NCHK;
        const int* ed = esel(k, e0, e1, e2, e3);
        int lo = cb * CHUNK, hi = min(EE, lo + CHUNK);
        for (int i = tid; i < NBK; i += 256) hist[i] = 0;
        __syncthreads();
        for (int i = lo + tid; i < hi; i += 256)
            atomicAdd(&hist[(k * NN + ed[EE + i]) >> 7], 1);
        __syncthreads();
        for (int i = tid; i < NBK; i += 256) {
            int c = hist[i];
            myb[i] = c ? atomicAdd(&gcur[i], c) : 0;
            hist[i] = 0;          // reuse as local cursor
        }
        __syncthreads();
        for (int i = lo + tid; i < hi; i += 256) {
            int src = ed[i], dst = ed[EE + i];
            int f = k * NN + dst, b = f >> 7;
            int p = atomicAdd(&hist[b], 1);
            bin[myb[b] + p] = ((unsigned)(f & 127) << 18) | (unsigned)(k * NN + src);
        }
    } else {
        float* Wl = shmem;
        float (*xl)[68] = (float(*)[68])(shmem + 4096);
        gemm_body(Wl, xl, bx - 196, tid, feat, (size_t)0,
                  nullptr, nullptr, nullptr, nullptr, rels, W,
                  nullptr, h_bf, 0);
    }
}

// ---- per-bucket finish: bin window -> compact-in-window CSR + off + deg + dinv ----
__global__ __launch_bounds__(256) void k_fine(
    const unsigned* __restrict__ bin, const int* __restrict__ gcur,
    int* __restrict__ off, unsigned short* __restrict__ deg16,
    float* __restrict__ dinv, int* __restrict__ csr) {
    __shared__ int cnt[BROW], noff[BROW], curl[BROW];
    __shared__ int wsum;
    int tid = threadIdx.x, b = blockIdx.x;
    if (tid < BROW) cnt[tid] = 0;
    __syncthreads();
    int s0 = b * CAP, s1 = gcur[b];
    for (int i = s0 + tid; i < s1; i += 256)
        atomicAdd(&cnt[bin[i] >> 18], 1);
    __syncthreads();
    int c0 = (tid < BROW) ? cnt[tid] : 0;
    int c = c0;
    #pragma unroll
    for (int d = 1; d < 64; d <<= 1) {
        int t = __shfl_up(c, d, 64);
        if ((tid & 63) >= d) c += t;
    }
    if (tid == 63) wsum = c;               // total of wave 0 (dsts 0..63)
    __syncthreads();
    if (tid < BROW) {
        int ex = c - c0 + ((tid >= 64) ? wsum : 0);   // exclusive within bucket
        noff[tid] = s0 + ex;
        curl[tid] = 0;
        int f = b * BROW + tid;
        if (f < NF) {
            off[f] = s0 + ex;
            deg16[f] = (unsigned short)c0;
            dinv[f] = rsqrtf((float)(c0 + 1));
        }
    }
    __syncthreads();
    for (int i = s0 + tid; i < s1; i += 256) {
        unsigned u = bin[i];
        int dl = u >> 18;
        int p = atomicAdd(&curl[dl], 1);
        csr[noff[dl] + p] = (int)(u & 0x3ffff);
    }
}

// ---- standalone GEMM (layers 1,2) ----
__global__ __launch_bounds__(256) void k_gemm(
    const float* __restrict__ prevbuf, size_t prev_ka_stride,
    const unsigned short* __restrict__ aggb, const float* __restrict__ stats,
    const float* __restrict__ gamma, const float* __restrict__ beta,
    const float* __restrict__ rels, const float* __restrict__ W,
    float* __restrict__ e1, unsigned short* __restrict__ h_bf, int mode) {
    __shared__ float Wl[4096];
    __shared__ float xl[16][68];
    gemm_body(Wl, xl, blockIdx.y * 3125 + blockIdx.x, threadIdx.x,
              prevbuf, prev_ka_stride, aggb, stats, gamma, beta,
              rels, W, e1, h_bf, mode);
}

// ---- gather: wave = 1 dst node; lane = (edge-group g of 8, col-chunk c8 of 8) ----
// BF16OUT=1 -> write bf16 agg; 0 -> write f32 (final output)
template <int BF16OUT>
__global__ __launch_bounds__(256) void k_gather(
    const unsigned short* __restrict__ h_bf, const int* __restrict__ csr,
    const int* __restrict__ off, const unsigned short* __restrict__ deg16,
    const float* __restrict__ dinv, const float* __restrict__ bias,
    void* __restrict__ dstbuf) {
    int tid = threadIdx.x;
    int lane = tid & 63, w = tid >> 6;
    int v = blockIdx.x * 4 + w;               // flat node id (relation-major)
    int g = lane >> 3, c8 = lane & 7;
    int s0 = off[v];
    int s1 = s0 + deg16[v];
    float di = dinv[v];
    float a0 = 0.f, a1 = 0.f, a2 = 0.f, a3 = 0.f;
    float a4 = 0.f, a5 = 0.f, a6 = 0.f, a7 = 0.f;
    const unsigned short* hcol = h_bf + c8 * 8;
    #pragma unroll 2
    for (int i = s0 + g; i < s1; i += 8) {
        int sf = csr[i];
        float nm = dinv[sf] * di;
        uint4 hv = *(const uint4*)(hcol + (size_t)sf * DD);
        a0 += __uint_as_float(hv.x << 16) * nm;
        a1 += __uint_as_float(hv.x & 0xffff0000u) * nm;
        a2 += __uint_as_float(hv.y << 16) * nm;
        a3 += __uint_as_float(hv.y & 0xffff0000u) * nm;
        a4 += __uint_as_float(hv.z << 16) * nm;
        a5 += __uint_as_float(hv.z & 0xffff0000u) * nm;
        a6 += __uint_as_float(hv.w << 16) * nm;
        a7 += __uint_as_float(hv.w & 0xffff0000u) * nm;
    }
    #pragma unroll
    for (int m = 8; m <= 32; m <<= 1) {
        a0 += __shfl_xor(a0, m); a1 += __shfl_xor(a1, m);
        a2 += __shfl_xor(a2, m); a3 += __shfl_xor(a3, m);
        a4 += __shfl_xor(a4, m); a5 += __shfl_xor(a5, m);
        a6 += __shfl_xor(a6, m); a7 += __shfl_xor(a7, m);
    }
    if (lane < 8) {
        float d2 = di * di;
        uint4 hd = *(const uint4*)(h_bf + (size_t)v * DD + lane * 8);
        f4 b0 = *(const f4*)(bias + lane * 8);
        f4 b1 = *(const f4*)(bias + lane * 8 + 4);
        f4 o0, o1;
        o0.x = b0.x + __uint_as_float(hd.x << 16) * d2 + a0;
        o0.y = b0.y + __uint_as_float(hd.x & 0xffff0000u) * d2 + a1;
        o0.z = b0.z + __uint_as_float(hd.y << 16) * d2 + a2;
        o0.w = b0.w + __uint_as_float(hd.y & 0xffff0000u) * d2 + a3;
        o1.x = b1.x + __uint_as_float(hd.z << 16) * d2 + a4;
        o1.y = b1.y + __uint_as_float(hd.z & 0xffff0000u) * d2 + a5;
        o1.z = b1.z + __uint_as_float(hd.w << 16) * d2 + a6;
        o1.w = b1.w + __uint_as_float(hd.w & 0xffff0000u) * d2 + a7;
        if (BF16OUT) {
            unsigned short* ab = (unsigned short*)dstbuf;
            uint4 st;
            st.x = (unsigned)f2b(o0.x) | ((unsigned)f2b(o0.y) << 16);
            st.y = (unsigned)f2b(o0.z) | ((unsigned)f2b(o0.w) << 16);
            st.z = (unsigned)f2b(o1.x) | ((unsigned)f2b(o1.y) << 16);
            st.w = (unsigned)f2b(o1.z) | ((unsigned)f2b(o1.w) << 16);
            *(uint4*)(ab + (size_t)v * DD + lane * 8) = st;
        } else {
            float* ob = (float*)dstbuf;
            *(f4*)(ob + (size_t)v * DD + lane * 8) = o0;
            *(f4*)(ob + (size_t)v * DD + lane * 8 + 4) = o1;
        }
    }
}

// ---- BN column stats (sum, sumsq) from bf16 agg ----
__global__ __launch_bounds__(256) void k_bnstats(
    const unsigned short* __restrict__ aggb, float* __restrict__ stats) {
    int ka = blockIdx.y;
    int col = threadIdx.x & 63;
    int w = threadIdx.x >> 6;
    long r0 = (long)blockIdx.x * 256 + w * 64;
    float s = 0.f, s2 = 0.f;
    size_t base = (size_t)ka * NN * DD;
    for (int i = 0; i < 64; ++i) {
        long r = r0 + i;
        if (r < NN) {
            float v = b2f(aggb[base + r * DD + col]);
            s += v;
            s2 += v * v;
        }
    }
    atomicAdd(stats + ka * 128 + col, s);
    atomicAdd(stats + ka * 128 + 64 + col, s2);
}

extern "C" void kernel_launch(void* const* d_in, const int* in_sizes, int n_in,
                              void* d_out, int out_size, void* d_ws, size_t ws_size,
                              hipStream_t stream) {
    const float* feat = (const float*)d_in[0];
    const float* poir = (const float*)d_in[1];
    const float* sr   = (const float*)d_in[2];
    const float* dr   = (const float*)d_in[3];
    const float* nr   = (const float*)d_in[4];
    const int* e_poi  = (const int*)d_in[5];
    const int* e_s    = (const int*)d_in[6];
    const int* e_d    = (const int*)d_in[7];
    const int* e_n    = (const int*)d_in[8];
    const float* gcnW = (const float*)d_in[9];
    const float* gcnb = (const float*)d_in[10];
    const float* bng  = (const float*)d_in[11];
    const float* bnb  = (const float*)d_in[12];
    const float* relW = (const float*)d_in[13];
    const float* relb = (const float*)d_in[14];

    float* out = (float*)d_out;
    float* rel_out = out + (size_t)4 * NN * DD;
    float* ws = (float*)d_ws;

    size_t o = 0;
    auto alloc = [&](size_t words) { o = (o + 3) & ~(size_t)3; size_t r = o; o += words; return r; };
    float* dinv     = ws + alloc(NF);
    float* rels_all = ws + alloc(1024);
    float* stats    = ws + alloc(1024);                    // [2 layers][512]
    int*   gcur     = (int*)(ws + alloc(NBK));
    int*   off      = (int*)(ws + alloc(NF));
    unsigned short* deg16 = (unsigned short*)(ws + alloc(NF / 2));
    unsigned* bin   = (unsigned*)(ws + alloc((size_t)NBK * CAP));
    int*   csr      = (int*)(ws + alloc((size_t)NBK * CAP));
    unsigned short* h_bf = (unsigned short*)(ws + alloc((size_t)2 * NN * DD));
    unsigned short* aggb = (unsigned short*)(ws + alloc((size_t)2 * NN * DD));
    float* e1       = ws + alloc((size_t)4 * NN * DD);

    const int* E0 = e_n;  const int* E1 = e_poi;
    const int* E2 = e_s;  const int* E3 = e_d;

    k_init<<<9, 256, 0, stream>>>(gcur, stats, nr, poir, sr, dr,
                                  relW, relb, rels_all, rel_out);
    k_bin_gemm0<<<12696, 256, 0, stream>>>(E0, E1, E2, E3, gcur, bin,
                                           feat, rels_all + 0, gcnW + 0, h_bf);
    k_fine<<<NBK, 256, 0, stream>>>(bin, gcur, off, deg16, dinv, csr);

    // layer 0
    k_gather<1><<<50000, 256, 0, stream>>>(h_bf, csr, off, deg16, dinv,
                                           gcnb + 0, aggb);
    k_bnstats<<<dim3(196, 4), 256, 0, stream>>>(aggb, stats + 0);

    // layer 1
    k_gemm<<<dim3(3125, 4), 256, 0, stream>>>(
        feat, (size_t)0, aggb, stats + 0, bng + 0, bnb + 0,
        rels_all + 256, gcnW + 4096, e1, h_bf, 1);
    k_gather<1><<<50000, 256, 0, stream>>>(h_bf, csr, off, deg16, dinv,
                                           gcnb + 64, aggb);
    k_bnstats<<<dim3(196, 4), 256, 0, stream>>>(aggb, stats + 512);

    // layer 2
    k_gemm<<<dim3(3125, 4), 256, 0, stream>>>(
        e1, (size_t)(NN * DD), aggb, stats + 512, bng + 64, bnb + 64,
        rels_all + 512, gcnW + 8192, nullptr, h_bf, 2);
    k_gather<0><<<50000, 256, 0, stream>>>(h_bf, csr, off, deg16, dinv,
                                           gcnb + 128, out);
}